// Round 1
// baseline (298.071 us; speedup 1.0000x reference)
//
#include <hip/hip_runtime.h>
#include <cstdint>

// Problem: B=8, LQ=LK=2048, DIM=128.
// out  [B,LQ,DIM] f32 = softmax(mask? -inf : QK^T/sqrt(D)) @ K
// attn [B,LQ,LK]  f32 = log_softmax(...)  (clamp logp to -1e30)
//
// R5: eliminate S-in-LDS (it capped occupancy at 2 blk/CU = 20%).
//     Flash-style two-pass: pass1 = swapped QK^T (S^T fragment: lane holds
//     row=l16, k=quad*4+r) -> mask u32/lane -> online softmax in registers ->
//     P regs feed mfma_16x16x16f16 PV directly (A-layout == S^T D-layout).
//     pass2 = recompute QK^T (L2-hot K frags) -> coalesced f32 logp stores.
//     LDS 66KB->34KB, __launch_bounds__(256,4): 4 blk/CU, 16 waves/CU.

#define DIMV 128
constexpr int BB = 8;
constexpr int LQ = 2048;
constexpr int LK = 2048;
constexpr float RTEMP = 0.08838834764831843f; // 1/sqrt(128)

typedef _Float16 half8 __attribute__((ext_vector_type(8)));
typedef _Float16 half4v __attribute__((ext_vector_type(4)));
typedef float float4v __attribute__((ext_vector_type(4)));

// ---- prep: build fragment-major Qf, Kf, Vf (fp16) in ws ----
// Qf/Kf[b]: [tile(128)][kk(4)][lane(64)][8]  elem [t*16+l16][kk*32+quad*8+e]
// Vf[b]:    [kt(128)][dp(4)][lane(64)][8]    elem e<4:  V[kt*16+quad*4+e][(2dp)*16+l16]
//                                            elem e>=4: V[kt*16+quad*4+e-4][(2dp+1)*16+l16]
__global__ __launch_bounds__(256) void prep_kernel(const float* __restrict__ q,
                                                   const float* __restrict__ ctx,
                                                   _Float16* __restrict__ Qf,
                                                   _Float16* __restrict__ Kf,
                                                   _Float16* __restrict__ Vf) {
    __shared__ float tile[32][132];
    const int tid  = threadIdx.x;
    const int mode = blockIdx.x >> 9;     // 0:Qf 1:Kf 2:Vf
    const int t    = blockIdx.x & 511;
    const int b    = t >> 6;
    const int r0   = (t & 63) * 32;       // 32 rows of 2048
    const float4* s4 = (const float4*)((mode == 0 ? q : ctx) + ((size_t)b * 2048 + r0) * DIMV);
    for (int v = 0; v < 4; v++) {
        int off = tid + v * 256;
        float4 f = s4[off];
        int row = off >> 5, c4 = (off & 31) * 4;
        tile[row][c4 + 0] = f.x; tile[row][c4 + 1] = f.y;
        tile[row][c4 + 2] = f.z; tile[row][c4 + 3] = f.w;
    }
    __syncthreads();
    if (mode < 2) {
        _Float16* dst = (mode == 0 ? Qf : Kf) + (size_t)b * (2048 * DIMV);
        for (int c = 0; c < 2; c++) {
            int chunk = tid + c * 256;                 // (t2, kk, lane)
            int t2 = chunk >> 8, kk = (chunk >> 6) & 3, lane = chunk & 63;
            int quad = lane >> 4, l16 = lane & 15;
            int r = t2 * 16 + l16, d0 = kk * 32 + quad * 8;
            half8 h;
            for (int e = 0; e < 8; e++) h[e] = (_Float16)tile[r][d0 + e];
            size_t tl = (size_t)(r0 >> 4) + t2;
            *(half8*)(dst + ((tl * 4 + kk) * 64 + lane) * 8) = h;
        }
    } else {
        _Float16* dst = Vf + (size_t)b * (2048 * DIMV);
        const int kt0 = r0 >> 4;
        for (int c = 0; c < 2; c++) {
            int chunk = tid + c * 256;                 // (ktl, dp, lane)
            int ktl = chunk >> 8, dp = (chunk >> 6) & 3, ln = chunk & 63;
            int qd = ln >> 4, s16 = ln & 15;
            half8 h;
            for (int e = 0; e < 4; e++) {
                h[e]     = (_Float16)tile[ktl * 16 + qd * 4 + e][(2 * dp) * 16 + s16];
                h[e + 4] = (_Float16)tile[ktl * 16 + qd * 4 + e][(2 * dp + 1) * 16 + s16];
            }
            *(half8*)(dst + ((((size_t)(kt0 + ktl)) * 4 + dp) * 64 + ln) * 8) = h;
        }
    }
}

// ---- main fused kernel: one block = (batch, 16 q-rows), 4 waves, 4 blk/CU ----
__global__ __launch_bounds__(256, 4)
void attn_kernel(const unsigned char* __restrict__ mask,
                 const _Float16* __restrict__ Qf, const _Float16* __restrict__ Kf,
                 const _Float16* __restrict__ Vf,
                 float* __restrict__ out, float* __restrict__ out_attn) {
    constexpr int TQ = 16;
    __shared__ __attribute__((aligned(16))) float pvred[4][TQ][132]; // 33,792 B
    __shared__ float redm[4][TQ];
    __shared__ float redl[4][TQ];
    __shared__ float swf[4][TQ];   // exp(m_w - M)
    __shared__ float mcl[TQ];      // M + log(L)
    __shared__ float rls[TQ];      // 1/L

    const int tid  = threadIdx.x;
    const int wave = tid >> 6;
    const int lane = tid & 63;
    const int l16  = lane & 15;
    const int quad = lane >> 4;

    const int b  = blockIdx.x & 7;          // XCD-aware batch mapping
    const int qt = blockIdx.x >> 3;
    const int q0 = qt * TQ;

    const _Float16* Qb = Qf + (size_t)b * (2048 * DIMV);
    const _Float16* Kb = Kf + (size_t)b * (2048 * DIMV);
    const _Float16* Vb = Vf + (size_t)b * (2048 * DIMV);

    // Q fragment (B-operand): lane holds Q[q0+l16][kk*32+quad*8+e]; lives through both passes
    half8 qfrag[4];
#pragma unroll
    for (int kk = 0; kk < 4; kk++)
        qfrag[kk] = *(const half8*)(Qb + (((size_t)qt * 4 + kk) * 64 + lane) * 8);

    // per-lane mask base: row q0+l16, this lane's 4 bytes start at col wave*512 + quad*4
    const unsigned char* mrow = mask + ((size_t)b * LQ + q0 + l16) * LK + wave * 512 + quad * 4;

    const _Float16* kbase = Kb + (size_t)wave * 32 * 2048; // wave owns k-tiles [wave*32, wave*32+32)
    const _Float16* vbase = Vb + (size_t)wave * 32 * 2048;

    const float NEGINF = -__builtin_inff();
    float m = -1e30f;       // finite sentinel: avoids (-inf)-(-inf) NaN on fully-masked tiles
    float l = 0.f;
    float4v oacc[8];        // PV partial: lane holds (q=quad*4+r, d=dt*16+l16)
#pragma unroll
    for (int dt = 0; dt < 8; dt++) oacc[dt] = (float4v){0.f, 0.f, 0.f, 0.f};

    // ---- pass 1: online softmax + PV over this wave's 512 k-cols ----
    for (int ct = 0; ct < 32; ct++) {
        const _Float16* kp = kbase + (size_t)ct * 2048;
        float4v st = (float4v){0.f, 0.f, 0.f, 0.f};
#pragma unroll
        for (int kk = 0; kk < 4; kk++) {
            half8 kf = *(const half8*)(kp + (kk * 64 + lane) * 8);
            // swapped: D = S^T tile, lane holds (k=quad*4+r, q=l16)
            st = __builtin_amdgcn_mfma_f32_16x16x32_f16(kf, qfrag[kk], st, 0, 0, 0);
        }
        const uint32_t mv = *(const uint32_t*)(mrow + ct * 16);
        float sv[4];
#pragma unroll
        for (int r = 0; r < 4; r++) {
            float v = st[r] * RTEMP;
            if ((mv >> (8 * r)) & 0xffu) v = NEGINF;
            sv[r] = v;
        }
        // row-max over the tile's 16 k (4 regs x 4 quads), replicated to all lanes of the row
        float tmax = fmaxf(fmaxf(sv[0], sv[1]), fmaxf(sv[2], sv[3]));
        tmax = fmaxf(tmax, __shfl_xor(tmax, 16));
        tmax = fmaxf(tmax, __shfl_xor(tmax, 32));
        const bool upd = tmax > m + 3.0f;   // defer-rescale threshold: p bounded by e^3
        if (__any(upd)) {
            const float mnew = upd ? tmax : m;
            const float sc = __expf(m - mnew);   // ==1 for rows not updating
            float scr[4];
#pragma unroll
            for (int r = 0; r < 4; r++) scr[r] = __shfl(sc, quad * 4 + r); // m-layout(row=l16) -> oacc-layout(row=quad*4+r)
            l *= sc;
#pragma unroll
            for (int dt = 0; dt < 8; dt++)
#pragma unroll
                for (int r = 0; r < 4; r++) oacc[dt][r] *= scr[r];
            m = mnew;
        }
        half4v pa;
        float psum = 0.f;
#pragma unroll
        for (int r = 0; r < 4; r++) {
            const float p = __expf(sv[r] - m);   // masked: exp(-inf)=0
            psum += p;
            pa[r] = (_Float16)p;
        }
        psum += __shfl_xor(psum, 16);
        psum += __shfl_xor(psum, 32);
        l += psum;
        // PV: pa is directly the 16x16x16 A-operand (i=l16=q, k=quad*4+e) — same lane, same regs
        const _Float16* vp = vbase + (size_t)ct * 2048;
#pragma unroll
        for (int dp = 0; dp < 4; dp++) {
            half8 v8 = *(const half8*)(vp + (dp * 64 + lane) * 8);
            half4v vlo = __builtin_shufflevector(v8, v8, 0, 1, 2, 3);
            half4v vhi = __builtin_shufflevector(v8, v8, 4, 5, 6, 7);
            oacc[2 * dp]     = __builtin_amdgcn_mfma_f32_16x16x16f16(pa, vlo, oacc[2 * dp],     0, 0, 0);
            oacc[2 * dp + 1] = __builtin_amdgcn_mfma_f32_16x16x16f16(pa, vhi, oacc[2 * dp + 1], 0, 0, 0);
        }
    }

    if (quad == 0) { redm[wave][l16] = m; redl[wave][l16] = l; }
    __syncthreads();
    if (tid < TQ) {
        const float m0 = redm[0][tid], m1 = redm[1][tid], m2 = redm[2][tid], m3 = redm[3][tid];
        const float M = fmaxf(fmaxf(m0, m1), fmaxf(m2, m3));
        const float e0 = __expf(m0 - M), e1 = __expf(m1 - M);
        const float e2 = __expf(m2 - M), e3 = __expf(m3 - M);
        const float L = e0 * redl[0][tid] + e1 * redl[1][tid]
                      + e2 * redl[2][tid] + e3 * redl[3][tid];
        swf[0][tid] = e0; swf[1][tid] = e1; swf[2][tid] = e2; swf[3][tid] = e3;
        mcl[tid] = M + __logf(L);
        rls[tid] = 1.0f / L;
    }
    __syncthreads();

    // dump scaled PV partials (2-way LDS aliasing only; conflict-free)
#pragma unroll
    for (int r = 0; r < 4; r++) {
        const float sc = swf[wave][quad * 4 + r];
#pragma unroll
        for (int dt = 0; dt < 8; dt++)
            pvred[wave][quad * 4 + r][dt * 16 + l16] = oacc[dt][r] * sc;
    }

    // ---- pass 2: recompute QK^T (K frags L2-hot), write logp from f32 scores ----
    const float mc = mcl[l16];
    float* oa = out_attn + ((size_t)b * LQ + q0 + l16) * LK + wave * 512 + quad * 4;
#pragma unroll 2
    for (int ct = 0; ct < 32; ct++) {
        const _Float16* kp = kbase + (size_t)ct * 2048;
        float4v st = (float4v){0.f, 0.f, 0.f, 0.f};
#pragma unroll
        for (int kk = 0; kk < 4; kk++) {
            half8 kf = *(const half8*)(kp + (kk * 64 + lane) * 8);
            st = __builtin_amdgcn_mfma_f32_16x16x32_f16(kf, qfrag[kk], st, 0, 0, 0);
        }
        const uint32_t mv = *(const uint32_t*)(mrow + ct * 16);
        float4v o;
#pragma unroll
        for (int r = 0; r < 4; r++) {
            float logp = st[r] * RTEMP - mc;
            if ((mv >> (8 * r)) & 0xffu) logp = -1.0e30f; // masked: finite sentinel
            o[r] = fmaxf(logp, -1.0e30f);
        }
        *(float4v*)(oa + ct * 16) = o;   // 64B contiguous per q-row per store
    }
    __syncthreads();

    // ---- final: out = (sum_w pvred[w]) / L, coalesced float4 ----
    {
        const int row = tid >> 4;
        const int c0 = (tid & 15) * 8;
        const float rcl = rls[row];
        float* op = out + ((size_t)b * LQ + q0 + row) * DIMV + c0;
#pragma unroll
        for (int h = 0; h < 2; h++) {
            const int c = c0 + h * 4;
            float4v a0 = *(const float4v*)&pvred[0][row][c];
            float4v a1 = *(const float4v*)&pvred[1][row][c];
            float4v a2 = *(const float4v*)&pvred[2][row][c];
            float4v a3 = *(const float4v*)&pvred[3][row][c];
            float4v v;
#pragma unroll
            for (int j = 0; j < 4; j++)
                v[j] = (a0[j] + a1[j] + a2[j] + a3[j]) * rcl;
            *(float4v*)(op + h * 4) = v;
        }
    }
}

extern "C" void kernel_launch(void* const* d_in, const int* in_sizes, int n_in,
                              void* d_out, int out_size, void* d_ws, size_t ws_size,
                              hipStream_t stream) {
    const float* q_f32 = (const float*)d_in[0];
    const float* c_f32 = (const float*)d_in[1];
    const unsigned char* mask = (const unsigned char*)d_in[2];

    float* out      = (float*)d_out;
    float* out_attn = out + (size_t)BB * LQ * DIMV;

    _Float16* Qf = (_Float16*)d_ws;                    // 4.19 MB each
    _Float16* Kf = Qf + (size_t)BB * LQ * DIMV;
    _Float16* Vf = Kf + (size_t)BB * LK * DIMV;

    prep_kernel<<<1536, 256, 0, stream>>>(q_f32, c_f32, Qf, Kf, Vf);
    attn_kernel<<<BB * (LQ / 16), 256, 0, stream>>>(mask, Qf, Kf, Vf, out, out_attn);
}